// Round 1
// baseline (945.211 us; speedup 1.0000x reference)
//
#include <hip/hip_runtime.h>
#include <stdint.h>

#define NB 8    // batch
#define NP 96   // premise positions
#define NH 96   // hypothesis positions
#define ND 128  // D1 == D2 == 128
#define TH 2    // h-values per block (128 KB contiguous K per block)

// out[b,p,h] = sum_i prem[b,p,i] * (sum_j K[p,h,i,j] * hyp[b,h,j])
// K (604 MB) is read exactly once -> pure streaming kernel; the whole game is
// keeping enough 16B loads in flight per thread to saturate HBM.
__global__ __launch_bounds__(256, 4) void interaction_kernel(
    const float* __restrict__ prem,   // fp32, (B, P, D)
    const float* __restrict__ hyp,    // fp32, (B, H, D)
    const float* __restrict__ kern,   // fp32, (P, H, D, D)
    float* __restrict__ out)          // fp32, (B, P, H)
{
    const int h0 = blockIdx.x * TH;
    const int p  = blockIdx.y;
    const int t  = threadIdx.x;

    __shared__ float ldsP[ND * NB];       // transposed: ldsP[i*8 + b] = prem[b,p,i]
    __shared__ float ldsH[TH][NB * ND];   // ldsH[hh][b*128 + j] = hyp[b,h0+hh,j]
    __shared__ float ldsR[TH][4 * NB];    // per-wave reduction buffer

    // ---- Stage premise + hypothesis: 256 threads x float4 ----
    {
        const int b = t & 7, c = t >> 3;          // c in [0,32): float4 chunk
        const float4 v = *(const float4*)(prem + ((size_t)(b * NP + p)) * ND + c * 4);
        const int i0 = c * 4;
        ldsP[(i0 + 0) * NB + b] = v.x;
        ldsP[(i0 + 1) * NB + b] = v.y;
        ldsP[(i0 + 2) * NB + b] = v.z;
        ldsP[(i0 + 3) * NB + b] = v.w;
        #pragma unroll
        for (int hh = 0; hh < TH; ++hh) {
            const float4 w = *(const float4*)(hyp + ((size_t)(b * NH + h0 + hh)) * ND + c * 4);
            *(float4*)&ldsH[hh][b * ND + c * 4] = w;
        }
    }
    __syncthreads();

    // ---- Thread mapping over the 128x128 fp32 K tile ----
    const int jc = t & 31;    // float4 chunk along j: half-wave covers a 512B row
    const int rg = t >> 5;    // 8 row-groups x 16 rows
    const int j0 = jc * 4;

    float acc[TH][NB];
    #pragma unroll
    for (int hh = 0; hh < TH; ++hh)
        #pragma unroll
        for (int b = 0; b < NB; ++b) acc[hh][b] = 0.f;

    #pragma unroll
    for (int hh = 0; hh < TH; ++hh) {
        const float4* kt = (const float4*)(kern + ((size_t)(p * NH + h0 + hh)) * (ND * ND));

        // Hypothesis fragment for this thread's j-chunk, all 8 batches (regs)
        float hyr[NB][4];
        #pragma unroll
        for (int b = 0; b < NB; ++b) {
            const float4 w = *(const float4*)&ldsH[hh][b * ND + j0];
            hyr[b][0] = w.x; hyr[b][1] = w.y; hyr[b][2] = w.z; hyr[b][3] = w.w;
        }

        // Two 8-deep pipelined phases: issue 8 dwordx4 loads, then consume.
        // (old version: unroll-4 with per-group vmcnt drain -> MLP-starved)
        #pragma unroll
        for (int half = 0; half < 2; ++half) {
            float4 kq[8];
            #pragma unroll
            for (int r = 0; r < 8; ++r)
                kq[r] = kt[(size_t)(rg * 16 + half * 8 + r) * 32 + jc];

            #pragma unroll
            for (int r = 0; r < 8; ++r) {
                const int i = rg * 16 + half * 8 + r;
                // same address across each half-wave -> LDS broadcast, conflict-free
                const float4 pa = *(const float4*)&ldsP[i * NB];
                const float4 pb = *(const float4*)&ldsP[i * NB + 4];
                const float pv[8] = {pa.x, pa.y, pa.z, pa.w, pb.x, pb.y, pb.z, pb.w};

                #pragma unroll
                for (int b = 0; b < NB; ++b) {
                    float s = kq[r].x * hyr[b][0];
                    s = fmaf(kq[r].y, hyr[b][1], s);
                    s = fmaf(kq[r].z, hyr[b][2], s);
                    s = fmaf(kq[r].w, hyr[b][3], s);
                    acc[hh][b] = fmaf(pv[b], s, acc[hh][b]);
                }
            }
        }
    }

    // ---- Reduce 256 threads -> TH*8 outputs ----
    #pragma unroll
    for (int hh = 0; hh < TH; ++hh)
        #pragma unroll
        for (int b = 0; b < NB; ++b)
            #pragma unroll
            for (int off = 32; off > 0; off >>= 1)
                acc[hh][b] += __shfl_down(acc[hh][b], off, 64);

    const int lane = t & 63, wave = t >> 6;
    if (lane == 0) {
        #pragma unroll
        for (int hh = 0; hh < TH; ++hh)
            #pragma unroll
            for (int b = 0; b < NB; ++b)
                ldsR[hh][wave * NB + b] = acc[hh][b];
    }
    __syncthreads();
    if (t < NB * TH) {
        const int b = t & 7, hh = t >> 3;
        const float s = ldsR[hh][b] + ldsR[hh][NB + b] + ldsR[hh][2 * NB + b] + ldsR[hh][3 * NB + b];
        out[(size_t)b * (NP * NH) + p * NH + (h0 + hh)] = s;
    }
}

extern "C" void kernel_launch(void* const* d_in, const int* in_sizes, int n_in,
                              void* d_out, int out_size, void* d_ws, size_t ws_size,
                              hipStream_t stream) {
    const float* prem = (const float*)d_in[0];
    const float* hyp  = (const float*)d_in[1];
    const float* kern = (const float*)d_in[2];
    float* out = (float*)d_out;

    dim3 grid(NH / TH, NP);   // blockIdx.x = h-tile, blockIdx.y = p
    dim3 block(256);
    interaction_kernel<<<grid, block, 0, stream>>>(prem, hyp, kern, out);
}

// Round 2
// 744.334 us; speedup vs baseline: 1.2699x; 1.2699x over previous
//
#include <hip/hip_runtime.h>
#include <stdint.h>

#define NB 8    // batch
#define NP 96   // premise positions
#define NH 96   // hypothesis positions
#define ND 128  // D1 == D2 == 128

// out[b,p,h] = sum_i prem[b,p,i] * (sum_j K[p,h,i,j] * hyp[b,h,j])
// K (604 MB) is streamed exactly once -> memory-bound; the lever is MLP:
// each thread issues ALL 16 of its float4 K-loads before consuming any.
// NOTE: no min-waves clamp -- round 1 showed __launch_bounds__(256,4)'s
// 128-VGPR cap spills kq[] to scratch and costs ~200 us.
__global__ __launch_bounds__(256) void interaction_kernel(
    const float* __restrict__ prem,   // fp32, (B, P, D)
    const float* __restrict__ hyp,    // fp32, (B, H, D)
    const float* __restrict__ kern,   // fp32, (P, H, D, D)
    float* __restrict__ out)          // fp32, (B, P, H)
{
    const int h = blockIdx.x;
    const int p = blockIdx.y;
    const int t = threadIdx.x;

    __shared__ float ldsP[ND * NB];   // transposed: ldsP[i*8 + b] = prem[b,p,i]
    __shared__ float ldsH[NB * ND];   // ldsH[b*128 + j] = hyp[b,h,j]
    __shared__ float ldsR[4 * NB];    // per-wave reduction buffer

    // ---- Stage premise + hypothesis: 256 threads x one float4 each ----
    {
        const int b = t & 7, c = t >> 3;           // c in [0,32): float4 chunk
        const float4 v = *(const float4*)(prem + ((size_t)(b * NP + p)) * ND + c * 4);
        const int i0 = c * 4;
        ldsP[(i0 + 0) * NB + b] = v.x;
        ldsP[(i0 + 1) * NB + b] = v.y;
        ldsP[(i0 + 2) * NB + b] = v.z;
        ldsP[(i0 + 3) * NB + b] = v.w;
        const float4 w = *(const float4*)(hyp + ((size_t)(b * NH + h)) * ND + c * 4);
        *(float4*)&ldsH[b * ND + c * 4] = w;
    }
    __syncthreads();

    // ---- Thread mapping over the 128x128 fp32 K tile ----
    const int jc = t & 31;    // which float4 chunk along j (half-wave = 512B row)
    const int rg = t >> 5;    // 8 row groups x 16 rows
    const int j0 = jc * 4;

    // Hypothesis fragment for this thread's j-chunk, all 8 batches
    float hyr[NB][4];
    #pragma unroll
    for (int b = 0; b < NB; ++b) {
        const float4 w = *(const float4*)&ldsH[b * ND + j0];
        hyr[b][0] = w.x; hyr[b][1] = w.y; hyr[b][2] = w.z; hyr[b][3] = w.w;
    }

    float acc[NB];
    #pragma unroll
    for (int b = 0; b < NB; ++b) acc[b] = 0.f;

    const float4* kb4 = (const float4*)(kern + ((size_t)(p * NH + h)) * (ND * ND));

    // ---- Issue the thread's ENTIRE K footprint (16 x dwordx4, 256B) ----
    float4 kq[16];
    #pragma unroll
    for (int r = 0; r < 16; ++r)
        kq[r] = kb4[(size_t)(rg * 16 + r) * 32 + jc];   // coalesced 512B row segs

    // ---- Consume in issue order (compiler emits descending vmcnt waits) ----
    #pragma unroll
    for (int r = 0; r < 16; ++r) {
        const int i = rg * 16 + r;
        // ldsP row i: same address across each half-wave -> broadcast, no conflict
        const float4 pa = *(const float4*)&ldsP[i * NB];
        const float4 pb = *(const float4*)&ldsP[i * NB + 4];
        const float pv[8] = {pa.x, pa.y, pa.z, pa.w, pb.x, pb.y, pb.z, pb.w};

        #pragma unroll
        for (int b = 0; b < NB; ++b) {
            float s = kq[r].x * hyr[b][0];
            s = fmaf(kq[r].y, hyr[b][1], s);
            s = fmaf(kq[r].z, hyr[b][2], s);
            s = fmaf(kq[r].w, hyr[b][3], s);
            acc[b] = fmaf(pv[b], s, acc[b]);
        }
    }

    // ---- Reduce 256 threads -> 8 outputs ----
    #pragma unroll
    for (int b = 0; b < NB; ++b) {
        #pragma unroll
        for (int off = 32; off > 0; off >>= 1)
            acc[b] += __shfl_down(acc[b], off, 64);
    }
    const int lane = t & 63, wave = t >> 6;
    if (lane == 0) {
        #pragma unroll
        for (int b = 0; b < NB; ++b) ldsR[wave * NB + b] = acc[b];
    }
    __syncthreads();
    if (t < NB) {
        const float s = ldsR[t] + ldsR[NB + t] + ldsR[2 * NB + t] + ldsR[3 * NB + t];
        out[(size_t)t * (NP * NH) + p * NH + h] = s;
    }
}

extern "C" void kernel_launch(void* const* d_in, const int* in_sizes, int n_in,
                              void* d_out, int out_size, void* d_ws, size_t ws_size,
                              hipStream_t stream) {
    const float* prem = (const float*)d_in[0];
    const float* hyp  = (const float*)d_in[1];
    const float* kern = (const float*)d_in[2];
    float* out = (float*)d_out;

    dim3 grid(NH, NP);   // blockIdx.x = h, blockIdx.y = p
    dim3 block(256);
    interaction_kernel<<<grid, block, 0, stream>>>(prem, hyp, kern, out);
}